// Round 2
// baseline (615.925 us; speedup 1.0000x reference)
//
#include <hip/hip_runtime.h>

#define BATCH   16384
#define KK      26
#define VDIM    128
#define NWORDS  100000

// DPP-shifted copy of x (0-fill out of row), added by caller. VALU-speed
// cross-lane: row_shr:n = 0x110|n, row_bcast15 = 0x142.
template <int CTRL>
__device__ __forceinline__ float dpp_mov(float x) {
    int xi = __builtin_bit_cast(int, x);
    int yi = __builtin_amdgcn_update_dpp(0, xi, CTRL, 0xF, 0xF, true);
    return __builtin_bit_cast(float, yi);
}

// ---------------------------------------------------------------------------
// Kernel 1: transpose O [VDIM, NWORDS] -> Ot [NWORDS, VDIM], PLUS fused
// D-row compaction: blocks 0..2047 copy 8 doc rows each (group g handles
// b = blk*8+g), D[doc_ids[b]] -> Dc[b]. The random-HBM D load is issued at
// kernel top and stored at kernel bottom, so its ~900-cycle latency hides
// under the BW-bound transpose work. BATCH = 2048*8 exactly.
// ---------------------------------------------------------------------------
__global__ __launch_bounds__(256) void transpose_O(const float* __restrict__ O,
                                                   const int* __restrict__ doc_ids,
                                                   const float* __restrict__ D,
                                                   float* __restrict__ Ot,
                                                   float* __restrict__ Dc) {
    __shared__ float tile[32][129];  // [w][v], pad breaks conflicts
    const int wbase = blockIdx.x * 32;
    const int t = threadIdx.x;
    const int g = t >> 5;            // 0..7
    const int l = t & 31;

    // Issue the random D gather first (consumed only at the very end).
    const int  b_dc   = blockIdx.x * 8 + g;
    const bool has_dc = (blockIdx.x < BATCH / 8);
    float4 dreg;
    if (has_dc) {
        const int doc = doc_ids[b_dc];   // 32 lanes same addr -> broadcast
        dreg = *(const float4*)&D[(size_t)doc * VDIM + l * 4];
    }

    #pragma unroll
    for (int i = 0; i < 4; ++i) {
        int idx = i * 256 + t;          // 0..1023
        int v = idx >> 3;               // 0..127
        int w4 = (idx & 7) * 4;         // 0,4,..,28
        float4 r = *(const float4*)&O[(size_t)v * NWORDS + wbase + w4];
        tile[w4 + 0][v] = r.x;
        tile[w4 + 1][v] = r.y;
        tile[w4 + 2][v] = r.z;
        tile[w4 + 3][v] = r.w;
    }
    __syncthreads();

    #pragma unroll
    for (int i = 0; i < 4; ++i) {
        int idx = i * 256 + t;
        int w = idx >> 5;               // 0..31
        int v = (idx & 31) * 4;         // 0,4,..,124
        *(float4*)&Ot[(size_t)(wbase + w) * VDIM + v] =
            *(const float4*)&tile[w][v];
    }

    if (has_dc)
        *(float4*)&Dc[(size_t)b_dc * VDIM + l * 4] = dreg;
}

// ---------------------------------------------------------------------------
// Kernel 2: gather-dot, 2 batches per block (8192 blocks). 8 groups of 32
// lanes; group g handles k = g, g+8, g+16, g+24 for both b's. Doc vectors
// now come from the compacted Dc (contiguous, L3-hot, no indirection) --
// the only remaining dependent chain is tn_ids -> Ot (L3-resident). All 8
// Ot row gathers issued unconditionally back-to-back (invalid k clamps to
// row 0) -> max MLP. DPP-based 32-lane reductions, no LDS, no syncthreads.
// ---------------------------------------------------------------------------
__global__ __launch_bounds__(256) void gather_dot(const int* __restrict__ tn_ids,
                                                  const float* __restrict__ Dc,
                                                  const float* __restrict__ Ot,
                                                  float* __restrict__ out) {
    const int b0 = blockIdx.x * 2;
    const int t = threadIdx.x;
    const int g = t >> 5;               // 0..7
    const int l = t & 31;

    // Contiguous compacted doc rows (no doc_ids indirection).
    const float4 dv0 = *(const float4*)&Dc[(size_t)b0 * VDIM + l * 4];
    const float4 dv1 = *(const float4*)&Dc[(size_t)(b0 + 1) * VDIM + l * 4];

    // All 8 word ids (2 b's x 4 k-slots). Clamp invalid slots to word 0.
    int word[2][4];
    #pragma unroll
    for (int j = 0; j < 4; ++j) {
        const int k = g + 8 * j;
        const bool ok = (k < KK);
        word[0][j] = ok ? tn_ids[b0 * KK + k] : 0;
        word[1][j] = ok ? tn_ids[(b0 + 1) * KK + k] : 0;
    }

    // All 8 row gathers issued back-to-back (no branches -> max MLP).
    float4 wv[2][4];
    #pragma unroll
    for (int m = 0; m < 2; ++m)
        #pragma unroll
        for (int j = 0; j < 4; ++j)
            wv[m][j] = *(const float4*)&Ot[(size_t)word[m][j] * VDIM + l * 4];

    #pragma unroll
    for (int m = 0; m < 2; ++m) {
        const float4 dv = m ? dv1 : dv0;
        const int base = (b0 + m) * KK;
        #pragma unroll
        for (int j = 0; j < 4; ++j) {
            const int k = g + 8 * j;
            float p = dv.x * wv[m][j].x + dv.y * wv[m][j].y
                    + dv.z * wv[m][j].z + dv.w * wv[m][j].w;
            p += dpp_mov<0x111>(p);     // row_shr:1
            p += dpp_mov<0x112>(p);     // row_shr:2
            p += dpp_mov<0x114>(p);     // row_shr:4
            p += dpp_mov<0x118>(p);     // row_shr:8  -> lane15/31 hold row sums
            p += dpp_mov<0x142>(p);     // row_bcast15 -> lane31 holds 32-lane sum
            if (l == 31 && k < KK) out[base + k] = p;
        }
    }
}

// ---------------------------------------------------------------------------
// Fallback (only if ws too small): direct strided column gather of O.
// ---------------------------------------------------------------------------
__global__ __launch_bounds__(256) void gather_dot_direct(const int* __restrict__ doc_ids,
                                                         const int* __restrict__ tn_ids,
                                                         const float* __restrict__ D,
                                                         const float* __restrict__ O,
                                                         float* __restrict__ out) {
    __shared__ float d_s[VDIM];
    const int b = blockIdx.x;

    if (threadIdx.x < VDIM) {
        const int doc = doc_ids[b];
        d_s[threadIdx.x] = D[(size_t)doc * VDIM + threadIdx.x];
    }
    __syncthreads();

    const int wave = threadIdx.x >> 6;
    const int lane = threadIdx.x & 63;
    const int v0 = lane * 2;
    const float2 dv = *(const float2*)&d_s[v0];

    for (int k = wave; k < KK; k += 4) {
        const int word = tn_ids[b * KK + k];
        float p = dv.x * O[(size_t)v0 * NWORDS + word]
                + dv.y * O[(size_t)(v0 + 1) * NWORDS + word];
        #pragma unroll
        for (int off = 32; off > 0; off >>= 1)
            p += __shfl_down(p, off);
        if (lane == 0) out[b * KK + k] = p;
    }
}

extern "C" void kernel_launch(void* const* d_in, const int* in_sizes, int n_in,
                              void* d_out, int out_size, void* d_ws, size_t ws_size,
                              hipStream_t stream) {
    // setup_inputs order: context_ids, doc_ids, target_noise_ids, D, O
    const int*   doc_ids = (const int*)d_in[1];
    const int*   tn_ids  = (const int*)d_in[2];
    const float* D       = (const float*)d_in[3];
    const float* O       = (const float*)d_in[4];
    float*       out     = (float*)d_out;

    const size_t ot_bytes = (size_t)NWORDS * VDIM * sizeof(float);
    const size_t dc_bytes = (size_t)BATCH * VDIM * sizeof(float);

    if (ws_size >= ot_bytes + dc_bytes) {
        float* Ot = (float*)d_ws;
        float* Dc = (float*)((char*)d_ws + ot_bytes);
        transpose_O<<<NWORDS / 32, 256, 0, stream>>>(O, doc_ids, D, Ot, Dc);
        gather_dot<<<BATCH / 2, 256, 0, stream>>>(tn_ids, Dc, Ot, out);
    } else {
        gather_dot_direct<<<BATCH, 256, 0, stream>>>(doc_ids, tn_ids, D, O, out);
    }
}